// Round 2
// 362.135 us; speedup vs baseline: 1.0359x; 1.0359x over previous
//
#include <hip/hip_runtime.h>

#define NEG_SLOPE 0.2f
#define G_SHIFT 8
#define G_SIZE  256      // dst nodes per bucket
#define NB1     256      // partition blocks (chunks)

typedef __attribute__((ext_vector_type(8))) short short8;
typedef __attribute__((ext_vector_type(4))) float floatx4;

// ---- bf16 helpers (manual RTNE; data is finite) ----
__device__ inline unsigned short f32_to_bf16(float f) {
    union { float f; unsigned int u; } c; c.f = f;
    unsigned int u = c.u;
    u += 0x7FFFu + ((u >> 16) & 1u);
    return (unsigned short)(u >> 16);
}
__device__ inline float bf16_lo(unsigned int u) {
    union { unsigned int u; float f; } c; c.u = u << 16; return c.f;
}
__device__ inline float bf16_hi(unsigned int u) {
    union { unsigned int u; float f; } c; c.u = u & 0xFFFF0000u; return c.f;
}

// ---------------------------------------------------------------------------
// Convert W (f32) to bf16 once per launch.
// ---------------------------------------------------------------------------
__global__ __launch_bounds__(256) void k_wconv(const float* __restrict__ W,
                                               unsigned short* __restrict__ Wb,
                                               int n) {
    int i = blockIdx.x * 256 + threadIdx.x;
    if (i < n) Wb[i] = f32_to_bf16(W[i]);
}

// ---------------------------------------------------------------------------
// K1: ft_bf16 = bf16(feat @ W.T) via MFMA 16x16x32_bf16 (validated R5).
// R8: manual RTNE conversion (round-0 bit-identical). The R7 cvt_pk asm is
// the prime suspect for the R7 numeric failure — do not reintroduce without
// an isolated numerics test.
// ---------------------------------------------------------------------------
__global__ __launch_bounds__(256) void k_gemm_mfma(const float* __restrict__ feat,
                                                   const unsigned short* __restrict__ Wb,
                                                   unsigned short* __restrict__ ftb,
                                                   int M) {
    const int tid  = threadIdx.x;
    const int wave = tid >> 6;
    const int lane = tid & 63;
    const int l16  = lane & 15;
    const int quad = lane >> 4;
    const int mw   = blockIdx.x * 64 + wave * 16;

    int arow = mw + l16;
    if (arow >= M) arow = M - 1;
    const float* aptr = feat + (size_t)arow * 256 + quad * 8;

    floatx4 acc[8];
#pragma unroll
    for (int t = 0; t < 8; ++t) acc[t] = (floatx4){0.f, 0.f, 0.f, 0.f};

#pragma unroll
    for (int k0 = 0; k0 < 256; k0 += 32) {
        float4 a0 = *(const float4*)(aptr + k0);
        float4 a1 = *(const float4*)(aptr + k0 + 4);
        short8 af;
        af[0] = (short)f32_to_bf16(a0.x);
        af[1] = (short)f32_to_bf16(a0.y);
        af[2] = (short)f32_to_bf16(a0.z);
        af[3] = (short)f32_to_bf16(a0.w);
        af[4] = (short)f32_to_bf16(a1.x);
        af[5] = (short)f32_to_bf16(a1.y);
        af[6] = (short)f32_to_bf16(a1.z);
        af[7] = (short)f32_to_bf16(a1.w);
#pragma unroll
        for (int t = 0; t < 8; ++t) {
            short8 bf = *(const short8*)(Wb + (size_t)(t * 16 + l16) * 256 + k0 + quad * 8);
            acc[t] = __builtin_amdgcn_mfma_f32_16x16x32_bf16(af, bf, acc[t], 0, 0, 0);
        }
    }

#pragma unroll
    for (int t = 0; t < 8; ++t) {
#pragma unroll
        for (int r = 0; r < 4; ++r) {
            int row = mw + quad * 4 + r;
            if (row < M)
                ftb[(size_t)row * 128 + t * 16 + l16] = f32_to_bf16(acc[t][r]);
        }
    }
}

// ---------------------------------------------------------------------------
// K2: el/er per (node, head) from bf16 ft.
// ---------------------------------------------------------------------------
__global__ __launch_bounds__(256) void k_elr(const unsigned short* __restrict__ ftb,
                                             const float* __restrict__ al,
                                             const float* __restrict__ ar,
                                             float* __restrict__ el,
                                             float* __restrict__ er,
                                             int NH) {
    int i = blockIdx.x * 256 + threadIdx.x;
    if (i >= NH) return;
    int h = i & 3;
    const unsigned int* f = (const unsigned int*)ftb + (size_t)i * 16;
    const float* lp = al + h * 32;
    const float* rp = ar + h * 32;
    float sl = 0.f, sr = 0.f;
#pragma unroll
    for (int j = 0; j < 16; ++j) {
        unsigned int u = f[j];
        float f0 = bf16_lo(u), f1 = bf16_hi(u);
        sl += f0 * lp[2 * j] + f1 * lp[2 * j + 1];
        sr += f0 * rp[2 * j] + f1 * rp[2 * j + 1];
    }
    el[i] = sl;
    er[i] = sr;
}

// ---------------------------------------------------------------------------
// Sort pass 1: per-(bucket,chunk) counts via LDS histogram. counts is
// bucket-major: counts[bk*NB1 + chunk].
// ---------------------------------------------------------------------------
__global__ __launch_bounds__(256) void k_count(const int* __restrict__ dst,
                                               int* __restrict__ counts,
                                               int E, int CH, int B) {
    __shared__ int hist[512];
    int j = blockIdx.x, t = threadIdx.x;
    for (int bk = t; bk < B; bk += 256) hist[bk] = 0;
    __syncthreads();
    int lo = j * CH, hi = min(E, lo + CH);
    for (int i = lo + t; i < hi; i += 256)
        atomicAdd(&hist[dst[i] >> G_SHIFT], 1);
    __syncthreads();
    for (int bk = t; bk < B; bk += 256) counts[bk * NB1 + j] = hist[bk];
}

// Exclusive scan level 1 (1024 elems/block). STRICTLY out-of-place (R2 bug).
__global__ __launch_bounds__(256) void k_scan1(const int* __restrict__ deg,
                                               int* __restrict__ offs,
                                               int* __restrict__ bsum, int n) {
    __shared__ int ls[256];
    int b = blockIdx.x, t = threadIdx.x;
    int base = b * 1024 + t * 4;
    int d0 = (base + 0 < n) ? deg[base + 0] : 0;
    int d1 = (base + 1 < n) ? deg[base + 1] : 0;
    int d2 = (base + 2 < n) ? deg[base + 2] : 0;
    int d3 = (base + 3 < n) ? deg[base + 3] : 0;
    int s = d0 + d1 + d2 + d3;
    ls[t] = s;
    __syncthreads();
    for (int o = 1; o < 256; o <<= 1) {
        int v = (t >= o) ? ls[t - o] : 0;
        __syncthreads();
        ls[t] += v;
        __syncthreads();
    }
    int excl = ls[t] - s;
    if (base + 0 < n) offs[base + 0] = excl;
    if (base + 1 < n) offs[base + 1] = excl + d0;
    if (base + 2 < n) offs[base + 2] = excl + d0 + d1;
    if (base + 3 < n) offs[base + 3] = excl + d0 + d1 + d2;
    if (t == 255) bsum[b] = ls[255];
}

__global__ __launch_bounds__(256) void k_scan2(int* __restrict__ bsum, int NB) {
    __shared__ int ls[256];
    int t = threadIdx.x;
    int v = (t < NB) ? bsum[t] : 0;
    ls[t] = v;
    __syncthreads();
    for (int o = 1; o < 256; o <<= 1) {
        int u = (t >= o) ? ls[t - o] : 0;
        __syncthreads();
        ls[t] += u;
        __syncthreads();
    }
    if (t < NB) bsum[t] = ls[t] - v;
}

// ---------------------------------------------------------------------------
// Sort pass 2: partition edges into bucket runs. Cursor = scanned + bsum
// added ON THE FLY (scan3 kernel eliminated).
// part entry = (local_dst << 17) | src  (src < 2^17, local_dst < 256).
// ---------------------------------------------------------------------------
__global__ __launch_bounds__(256) void k_partition(const int* __restrict__ src,
                                                   const int* __restrict__ dst,
                                                   const int* __restrict__ scanned,
                                                   const int* __restrict__ bsum,
                                                   int* __restrict__ part,
                                                   int E, int CH, int B) {
    __shared__ int curs[512];
    int j = blockIdx.x, t = threadIdx.x;
    for (int bk = t; bk < B; bk += 256) {
        int idx = bk * NB1 + j;
        curs[bk] = scanned[idx] + bsum[idx >> 10];
    }
    __syncthreads();
    int lo = j * CH, hi = min(E, lo + CH);
    for (int i = lo + t; i < hi; i += 256) {
        int d = dst[i];
        int bk = d >> G_SHIFT;
        int pos = atomicAdd(&curs[bk], 1);
        if (pos >= 0 && pos < E)
            part[pos] = ((d & (G_SIZE - 1)) << 17) | src[i];
    }
}

// ---------------------------------------------------------------------------
// Sort pass 3: one workgroup per bucket; bsum added on the fly.
// ---------------------------------------------------------------------------
__global__ __launch_bounds__(256) void k_bucket(const int* __restrict__ scanned,
                                                const int* __restrict__ bsum,
                                                const int* __restrict__ part,
                                                int* __restrict__ offs,
                                                int* __restrict__ esrc,
                                                int E, int B, int N) {
    __shared__ int hist[256], ls[256], curs[256];
    int b = blockIdx.x, t = threadIdx.x;
    int i0 = b * NB1;
    int start = scanned[i0] + bsum[i0 >> 10];
    int end = E;
    if (b < B - 1) {
        int i1 = (b + 1) * NB1;
        end = scanned[i1] + bsum[i1 >> 10];
    }

    hist[t] = 0;
    __syncthreads();
    for (int i = start + t; i < end; i += 256)
        atomicAdd(&hist[(part[i] >> 17) & 255], 1);
    __syncthreads();

    int h = hist[t];
    ls[t] = h;
    __syncthreads();
    for (int o = 1; o < 256; o <<= 1) {
        int v = (t >= o) ? ls[t - o] : 0;
        __syncthreads();
        ls[t] += v;
        __syncthreads();
    }
    int excl = ls[t] - h;
    curs[t] = excl;
    int node = b * G_SIZE + t;
    if (node < N) offs[node] = start + excl;
    if (b == B - 1 && t == 0) offs[N] = E;
    __syncthreads();

    for (int i = start + t; i < end; i += 256) {
        int p = part[i];
        int pos = start + atomicAdd(&curs[(p >> 17) & 255], 1);
        if (pos >= 0 && pos < E) esrc[pos] = p & 0x1FFFF;
    }
}

// ---------------------------------------------------------------------------
// K4 (CSR): one wave per dst node, TWO-PHASE over 16-edge passes.
// R8: branch-free zero-padded 16-slot pass with ALL gathers issued before
// any consume (16 outstanding loads/wave, was 2) — the latency-hiding lever.
// Both w AND s broadcast via ds_bpermute (exact round-0 semantics; the R7
// readlane variant is retired together with the cvt_pk change).
//   - pad slots (e >= cnt) carry w=0, s=0 from phase 1: contribute exactly
//     0.0f, and their gathers hit the single cached ft[0] line.
// No atomics, no __syncthreads (waves independent).
// ---------------------------------------------------------------------------
__global__ __launch_bounds__(256) void k_aggr_csr(const int* __restrict__ offs,
                                                  const int* __restrict__ esrc,
                                                  const float* __restrict__ el,
                                                  const float* __restrict__ er,
                                                  const unsigned short* __restrict__ ftb,
                                                  const float* __restrict__ bias,
                                                  float* __restrict__ out,
                                                  int N) {
    int node = blockIdx.x * 4 + (threadIdx.x >> 6);
    if (node >= N) return;
    int lane = threadIdx.x & 63;
    int h1 = lane & 3;            // head this lane evaluates in phase 1
    int h2b = (lane >> 4) << 2;   // byte offset of this lane's output head
    float er1 = er[node * 4 + h1];

    int start = offs[node];
    int deg   = offs[node + 1] - start;

    float2 acc = make_float2(0.f, 0.f);
    float  wsum = 0.f;
    const unsigned int* ftu = (const unsigned int*)ftb;

    int p = 0;
    while (p < deg) {
        int cnt = min(16, deg - p);
        // ---- phase 1: lane group (4e..4e+3) computes (s, w) for edge p+e
        float w = 0.f;
        int   s = 0;
        int   e = lane >> 2;
        if (e < cnt) {
            s = esrc[start + p + e];
            float x = el[s * 4 + h1] + er1;
            x = x >= 0.f ? x : NEG_SLOPE * x;
            w = __expf(x);
        }
        // ---- phase 2: branch-free 16-slot pass, all gathers in flight
        float        wv[16];
        unsigned int uv[16];
#pragma unroll
        for (int j = 0; j < 16; ++j) {
            int ib = (j << 4) + h2b;   // byte idx of lane 4j + h2
            wv[j] = __int_as_float(
                __builtin_amdgcn_ds_bpermute(ib, __float_as_int(w)));
            int sj = __builtin_amdgcn_ds_bpermute(ib, s);
            uv[j] = ftu[(size_t)sj * 64 + lane];
        }
#pragma unroll
        for (int j = 0; j < 16; ++j) {
            wsum  += wv[j];
            acc.x += wv[j] * bf16_lo(uv[j]);
            acc.y += wv[j] * bf16_hi(uv[j]);
        }
        p += cnt;
    }
    float scale = 1.0f / fmaxf(wsum, 1e-16f);
    float2 bv = ((const float2*)bias)[lane];
    float2 o;
    o.x = acc.x * scale + bv.x;
    o.y = acc.y * scale + bv.y;
    ((float2*)out)[(size_t)node * 64 + lane] = o;
}

// ---------------------------------------------------------------------------
// Fallback (atomic) path — only if ws can't hold sort scratch.
// ---------------------------------------------------------------------------
__global__ __launch_bounds__(256) void k_init_fb(float* __restrict__ out,
                                                 const float* __restrict__ bias,
                                                 float* __restrict__ esum,
                                                 int n_out, int n_esum) {
    int i = blockIdx.x * 256 + threadIdx.x;
    if (i < n_out)  out[i]  = bias[i & 127];
    if (i < n_esum) esum[i] = 0.0f;
}

__global__ __launch_bounds__(256) void k_esum_fb(const int* __restrict__ src,
                                                 const int* __restrict__ dst,
                                                 const float* __restrict__ el,
                                                 const float* __restrict__ er,
                                                 float* __restrict__ esum,
                                                 int E4) {
    int i = blockIdx.x * 256 + threadIdx.x;
    if (i >= E4) return;
    int e = i >> 2, h = i & 3;
    int s = src[e], d = dst[e];
    float x = el[s * 4 + h] + er[d * 4 + h];
    x = x >= 0.f ? x : NEG_SLOPE * x;
    atomicAdd(&esum[d * 4 + h], __expf(x));
}

__global__ __launch_bounds__(256) void k_aggr_fb(const int* __restrict__ src,
                                                 const int* __restrict__ dst,
                                                 const float* __restrict__ el,
                                                 const float* __restrict__ er,
                                                 const float* __restrict__ esum,
                                                 const unsigned short* __restrict__ ftb,
                                                 float* __restrict__ out,
                                                 int E) {
    int i = blockIdx.x * 256 + threadIdx.x;
    int e = i >> 6;
    if (e >= E) return;
    int c = i & 63;
    int h = c >> 4;
    int s = src[e], d = dst[e];
    float x = el[s * 4 + h] + er[d * 4 + h];
    x = x >= 0.f ? x : NEG_SLOPE * x;
    float a = __expf(x) / fmaxf(esum[d * 4 + h], 1e-16f);
    unsigned int u = ((const unsigned int*)ftb)[(size_t)s * 64 + c];
    float* o = out + (size_t)d * 128 + c * 2;
    atomicAdd(o + 0, bf16_lo(u) * a);
    atomicAdd(o + 1, bf16_hi(u) * a);
}

// ---------------------------------------------------------------------------
extern "C" void kernel_launch(void* const* d_in, const int* in_sizes, int n_in,
                              void* d_out, int out_size, void* d_ws, size_t ws_size,
                              hipStream_t stream) {
    const float* feat   = (const float*)d_in[0];
    const int*   src    = (const int*)d_in[1];
    const int*   dst    = (const int*)d_in[2];
    const float* W      = (const float*)d_in[3];
    const float* attn_l = (const float*)d_in[4];
    const float* attn_r = (const float*)d_in[5];
    const float* bias   = (const float*)d_in[6];

    const int N  = in_sizes[0] / 256;   // 100000
    const int E  = in_sizes[1];         // 1600000
    const int NW = in_sizes[3];         // 32768
    float* out = (float*)d_out;

    const int B  = (N + G_SIZE - 1) / G_SIZE;       // 391 buckets
    const int CH = (E + NB1 - 1) / NB1;             // 6250 edges/chunk
    const int n2 = B * NB1;                         // 100096 count entries

    // ws layout: ftb[N*128 bf16] | Wb[NW bf16] | el[N*4] | er[N*4] |
    //            offs[N+1] | counts[n2] | scanned[n2] | bsum[256] |
    //            part[E] | esrc[E]
    unsigned short* ftb = (unsigned short*)d_ws;
    unsigned short* Wb  = ftb + (size_t)N * 128;
    float* el = (float*)(Wb + NW);
    float* er = el + (size_t)N * 4;
    int* offs    = (int*)(er + (size_t)N * 4);
    int* counts  = offs + (N + 1);
    int* scanned = counts + n2;
    int* bsum    = scanned + n2;
    int* part    = bsum + 256;
    int* esrc    = part + E;
    size_t need = (size_t)((char*)(esrc + E) - (char*)d_ws);

    k_wconv<<<(NW + 255) / 256, 256, 0, stream>>>(W, Wb, NW);
    k_gemm_mfma<<<(N + 63) / 64, 256, 0, stream>>>(feat, Wb, ftb, N);
    k_elr<<<(N * 4 + 255) / 256, 256, 0, stream>>>(ftb, attn_l, attn_r, el, er, N * 4);

    if (ws_size >= need) {
        const int NBs = (n2 + 1023) / 1024;   // 98 <= 256
        k_count<<<NB1, 256, 0, stream>>>(dst, counts, E, CH, B);
        k_scan1<<<NBs, 256, 0, stream>>>(counts, scanned, bsum, n2);   // out-of-place
        k_scan2<<<1, 256, 0, stream>>>(bsum, NBs);
        k_partition<<<NB1, 256, 0, stream>>>(src, dst, scanned, bsum, part, E, CH, B);
        k_bucket<<<B, 256, 0, stream>>>(scanned, bsum, part, offs, esrc, E, B, N);
        k_aggr_csr<<<(N + 3) / 4, 256, 0, stream>>>(offs, esrc, el, er, ftb, bias, out, N);
    } else {
        float* esum = (float*)(er + (size_t)N * 4);
        k_init_fb<<<(N * 128 + 255) / 256, 256, 0, stream>>>(out, bias, esum, N * 128, N * 4);
        k_esum_fb<<<(E * 4 + 255) / 256, 256, 0, stream>>>(src, dst, el, er, esum, E * 4);
        k_aggr_fb<<<((size_t)E * 64 + 255) / 256, 256, 0, stream>>>(src, dst, el, er, esum, ftb, out, E);
    }
}

// Round 3
// 343.225 us; speedup vs baseline: 1.0929x; 1.0551x over previous
//
#include <hip/hip_runtime.h>

#define NEG_SLOPE 0.2f
#define G_SHIFT 8
#define G_SIZE  256      // dst nodes per bucket
#define NB1     256      // partition blocks (chunks)

typedef __attribute__((ext_vector_type(8))) short short8;
typedef __attribute__((ext_vector_type(4))) float floatx4;

// ---- bf16 helpers (manual RTNE; data is finite) ----
__device__ inline unsigned short f32_to_bf16(float f) {
    union { float f; unsigned int u; } c; c.f = f;
    unsigned int u = c.u;
    u += 0x7FFFu + ((u >> 16) & 1u);
    return (unsigned short)(u >> 16);
}
__device__ inline float bf16_lo(unsigned int u) {
    union { unsigned int u; float f; } c; c.u = u << 16; return c.f;
}
__device__ inline float bf16_hi(unsigned int u) {
    union { unsigned int u; float f; } c; c.u = u & 0xFFFF0000u; return c.f;
}

// ---------------------------------------------------------------------------
// Convert W (f32) to bf16 once per launch.
// ---------------------------------------------------------------------------
__global__ __launch_bounds__(256) void k_wconv(const float* __restrict__ W,
                                               unsigned short* __restrict__ Wb,
                                               int n) {
    int i = blockIdx.x * 256 + threadIdx.x;
    if (i < n) Wb[i] = f32_to_bf16(W[i]);
}

// ---------------------------------------------------------------------------
// K1 (R9 rewrite): ft_bf16 = bf16(feat @ W.T), latency-fix edition.
// R8 diagnosis: MfmaUtil 2.9 / VALUBusy 5.6 / HBM 12% => A-stream latency
// bound (~1.6 KB in flight/CU ~= 1.26 TB/s by Little's law; matches).
// Fix: A staged via global_load_lds (in-flight bytes live in LDS, not VGPRs):
//   - 4-buffer pipeline of 64row x 32k f32 chunks (8 KB), 2-3 chunks
//     outstanding per block => 16-24 KB in flight/CU at 2 blocks/CU.
//   - counted s_waitcnt vmcnt(4/2/0) + raw s_barrier (NOT __syncthreads,
//     which drains vmcnt(0) and kills the pipeline).
//   - gl_lds dest must be linear => XOR-swizzle applied on the GLOBAL source
//     (lane i loads cols ((i&7)^(i>>3))*4); LDS reads use
//     byte = (r*128 + q*32) ^ ((r&7)<<4) => conflict-free b128 reads.
//   - B (64 KB) in REGISTERS, N-split across waves: wave (wm,wn) computes
//     rows wm*32..+31 x cols wn*64..+63 (4 t-frags x 8 k-frags = 128 VGPR).
// Numerics bit-identical to R8: same RTNE conversion, same MFMA, same k0
// accumulation order.
// ---------------------------------------------------------------------------
__global__ __launch_bounds__(256) void k_gemm_mfma(const float* __restrict__ feat,
                                                   const unsigned short* __restrict__ Wb,
                                                   unsigned short* __restrict__ ftb,
                                                   int M) {
    __shared__ float Abuf[4][2048];   // 4 bufs x (64 rows x 32 k) f32 = 32 KB

    const int tid  = threadIdx.x;
    const int w    = tid >> 6;        // wave 0..3
    const int lane = tid & 63;
    const int l16  = lane & 15;
    const int quad = lane >> 4;
    const int wm   = w & 1;           // M-half of the 64-row tile
    const int wn   = w >> 1;          // N-half (cols wn*64..wn*64+63)
    const int tile = blockIdx.x * 64;

    // ---- B fragments in registers: b[t][kc], t=0..3 (cols wn*64+t*16+l16),
    //      kc=0..7 (k = kc*32 + quad*8). Loaded once from L2 (Wb = 64 KB).
    short8 b[4][8];
#pragma unroll
    for (int t = 0; t < 4; ++t) {
        const unsigned short* bp =
            Wb + (size_t)((wn * 4 + t) * 16 + l16) * 256 + quad * 8;
#pragma unroll
        for (int kc = 0; kc < 8; ++kc)
            b[t][kc] = *(const short8*)(bp + kc * 32);
    }

    // ---- A staging: per wave 2 gl_lds per chunk (8 rows of 32 f32 each).
    // Source swizzle: lane i covers local row (w*2+q)*8 + (i>>3),
    // k-block c4 = ((i&7) ^ (i>>3)) so that linear LDS == swizzled layout.
    const int rloc = lane >> 3;
    const int c4   = ((lane & 7) ^ rloc) * 4;
    int gr0 = tile + (w * 2 + 0) * 8 + rloc; if (gr0 >= M) gr0 = M - 1;
    int gr1 = tile + (w * 2 + 1) * 8 + rloc; if (gr1 >= M) gr1 = M - 1;
    const float* g0 = feat + (size_t)gr0 * 256 + c4;
    const float* g1 = feat + (size_t)gr1 * 256 + c4;

#define STAGE(JC) do {                                                          \
    __builtin_amdgcn_global_load_lds(                                           \
        (const __attribute__((address_space(1))) unsigned int*)(g0 + (JC) * 32),\
        (__attribute__((address_space(3))) unsigned int*)&Abuf[(JC) & 3][(w * 2 + 0) * 256], \
        16, 0, 0);                                                              \
    __builtin_amdgcn_global_load_lds(                                           \
        (const __attribute__((address_space(1))) unsigned int*)(g1 + (JC) * 32),\
        (__attribute__((address_space(3))) unsigned int*)&Abuf[(JC) & 3][(w * 2 + 1) * 256], \
        16, 0, 0);                                                              \
} while (0)

    floatx4 acc[2][4];
#pragma unroll
    for (int m = 0; m < 2; ++m)
#pragma unroll
        for (int t = 0; t < 4; ++t)
            acc[m][t] = (floatx4){0.f, 0.f, 0.f, 0.f};

    // Prologue: 3 chunks in flight.
    STAGE(0); STAGE(1); STAGE(2);

    const int sw = (l16 & 7) << 4;    // read-side XOR (r&7)<<4, r = ..+l16

    // One K-step: wait own chunk-J loads (counted, never drain the pipe),
    // barrier (all waves' parts of chunk J landed), fence, prefetch J+3
    // (buffer (J-1)&3 — free: every wave passed the barrier, so all finished
    // computing chunk J-1), then compute chunk J.
#define KSTEP(J, VM) do {                                                       \
    asm volatile("s_waitcnt vmcnt(" #VM ")" ::: "memory");                      \
    __builtin_amdgcn_s_barrier();                                               \
    asm volatile("" ::: "memory");                                              \
    if ((J) + 3 < 8) STAGE((J) + 3);                                            \
    const char* ab = (const char*)&Abuf[(J) & 3][0];                            \
    _Pragma("unroll")                                                           \
    for (int m = 0; m < 2; ++m) {                                               \
        int base = (wm * 32 + m * 16 + l16) * 128 + quad * 32;                  \
        float4 alo = *(const float4*)(ab + ((base)      ^ sw));                 \
        float4 ahi = *(const float4*)(ab + ((base + 16) ^ sw));                 \
        short8 af;                                                              \
        af[0] = (short)f32_to_bf16(alo.x);                                      \
        af[1] = (short)f32_to_bf16(alo.y);                                      \
        af[2] = (short)f32_to_bf16(alo.z);                                      \
        af[3] = (short)f32_to_bf16(alo.w);                                      \
        af[4] = (short)f32_to_bf16(ahi.x);                                      \
        af[5] = (short)f32_to_bf16(ahi.y);                                      \
        af[6] = (short)f32_to_bf16(ahi.z);                                      \
        af[7] = (short)f32_to_bf16(ahi.w);                                      \
        _Pragma("unroll")                                                       \
        for (int t = 0; t < 4; ++t)                                             \
            acc[m][t] = __builtin_amdgcn_mfma_f32_16x16x32_bf16(                \
                af, b[t][(J)], acc[m][t], 0, 0, 0);                             \
    }                                                                           \
} while (0)

    KSTEP(0, 4); KSTEP(1, 4); KSTEP(2, 4); KSTEP(3, 4);
    KSTEP(4, 4); KSTEP(5, 4); KSTEP(6, 2); KSTEP(7, 0);

#undef KSTEP
#undef STAGE

    // Epilogue: same validated C/D mapping as R8 (col = l16, rows quad*4+r).
#pragma unroll
    for (int m = 0; m < 2; ++m) {
#pragma unroll
        for (int t = 0; t < 4; ++t) {
#pragma unroll
            for (int r = 0; r < 4; ++r) {
                int row = tile + wm * 32 + m * 16 + quad * 4 + r;
                if (row < M)
                    ftb[(size_t)row * 128 + (wn * 4 + t) * 16 + l16] =
                        f32_to_bf16(acc[m][t][r]);
            }
        }
    }
}

// ---------------------------------------------------------------------------
// K2: el/er per (node, head) from bf16 ft.
// ---------------------------------------------------------------------------
__global__ __launch_bounds__(256) void k_elr(const unsigned short* __restrict__ ftb,
                                             const float* __restrict__ al,
                                             const float* __restrict__ ar,
                                             float* __restrict__ el,
                                             float* __restrict__ er,
                                             int NH) {
    int i = blockIdx.x * 256 + threadIdx.x;
    if (i >= NH) return;
    int h = i & 3;
    const unsigned int* f = (const unsigned int*)ftb + (size_t)i * 16;
    const float* lp = al + h * 32;
    const float* rp = ar + h * 32;
    float sl = 0.f, sr = 0.f;
#pragma unroll
    for (int j = 0; j < 16; ++j) {
        unsigned int u = f[j];
        float f0 = bf16_lo(u), f1 = bf16_hi(u);
        sl += f0 * lp[2 * j] + f1 * lp[2 * j + 1];
        sr += f0 * rp[2 * j] + f1 * rp[2 * j + 1];
    }
    el[i] = sl;
    er[i] = sr;
}

// ---------------------------------------------------------------------------
// Sort pass 1: per-(bucket,chunk) counts via LDS histogram. counts is
// bucket-major: counts[bk*NB1 + chunk].
// ---------------------------------------------------------------------------
__global__ __launch_bounds__(256) void k_count(const int* __restrict__ dst,
                                               int* __restrict__ counts,
                                               int E, int CH, int B) {
    __shared__ int hist[512];
    int j = blockIdx.x, t = threadIdx.x;
    for (int bk = t; bk < B; bk += 256) hist[bk] = 0;
    __syncthreads();
    int lo = j * CH, hi = min(E, lo + CH);
    for (int i = lo + t; i < hi; i += 256)
        atomicAdd(&hist[dst[i] >> G_SHIFT], 1);
    __syncthreads();
    for (int bk = t; bk < B; bk += 256) counts[bk * NB1 + j] = hist[bk];
}

// Exclusive scan level 1 (1024 elems/block). STRICTLY out-of-place (R2 bug).
__global__ __launch_bounds__(256) void k_scan1(const int* __restrict__ deg,
                                               int* __restrict__ offs,
                                               int* __restrict__ bsum, int n) {
    __shared__ int ls[256];
    int b = blockIdx.x, t = threadIdx.x;
    int base = b * 1024 + t * 4;
    int d0 = (base + 0 < n) ? deg[base + 0] : 0;
    int d1 = (base + 1 < n) ? deg[base + 1] : 0;
    int d2 = (base + 2 < n) ? deg[base + 2] : 0;
    int d3 = (base + 3 < n) ? deg[base + 3] : 0;
    int s = d0 + d1 + d2 + d3;
    ls[t] = s;
    __syncthreads();
    for (int o = 1; o < 256; o <<= 1) {
        int v = (t >= o) ? ls[t - o] : 0;
        __syncthreads();
        ls[t] += v;
        __syncthreads();
    }
    int excl = ls[t] - s;
    if (base + 0 < n) offs[base + 0] = excl;
    if (base + 1 < n) offs[base + 1] = excl + d0;
    if (base + 2 < n) offs[base + 2] = excl + d0 + d1;
    if (base + 3 < n) offs[base + 3] = excl + d0 + d1 + d2;
    if (t == 255) bsum[b] = ls[255];
}

__global__ __launch_bounds__(256) void k_scan2(int* __restrict__ bsum, int NB) {
    __shared__ int ls[256];
    int t = threadIdx.x;
    int v = (t < NB) ? bsum[t] : 0;
    ls[t] = v;
    __syncthreads();
    for (int o = 1; o < 256; o <<= 1) {
        int u = (t >= o) ? ls[t - o] : 0;
        __syncthreads();
        ls[t] += u;
        __syncthreads();
    }
    if (t < NB) bsum[t] = ls[t] - v;
}

// ---------------------------------------------------------------------------
// Sort pass 2: partition edges into bucket runs. Cursor = scanned + bsum
// added ON THE FLY (scan3 kernel eliminated).
// part entry = (local_dst << 17) | src  (src < 2^17, local_dst < 256).
// ---------------------------------------------------------------------------
__global__ __launch_bounds__(256) void k_partition(const int* __restrict__ src,
                                                   const int* __restrict__ dst,
                                                   const int* __restrict__ scanned,
                                                   const int* __restrict__ bsum,
                                                   int* __restrict__ part,
                                                   int E, int CH, int B) {
    __shared__ int curs[512];
    int j = blockIdx.x, t = threadIdx.x;
    for (int bk = t; bk < B; bk += 256) {
        int idx = bk * NB1 + j;
        curs[bk] = scanned[idx] + bsum[idx >> 10];
    }
    __syncthreads();
    int lo = j * CH, hi = min(E, lo + CH);
    for (int i = lo + t; i < hi; i += 256) {
        int d = dst[i];
        int bk = d >> G_SHIFT;
        int pos = atomicAdd(&curs[bk], 1);
        if (pos >= 0 && pos < E)
            part[pos] = ((d & (G_SIZE - 1)) << 17) | src[i];
    }
}

// ---------------------------------------------------------------------------
// Sort pass 3: one workgroup per bucket; bsum added on the fly.
// ---------------------------------------------------------------------------
__global__ __launch_bounds__(256) void k_bucket(const int* __restrict__ scanned,
                                                const int* __restrict__ bsum,
                                                const int* __restrict__ part,
                                                int* __restrict__ offs,
                                                int* __restrict__ esrc,
                                                int E, int B, int N) {
    __shared__ int hist[256], ls[256], curs[256];
    int b = blockIdx.x, t = threadIdx.x;
    int i0 = b * NB1;
    int start = scanned[i0] + bsum[i0 >> 10];
    int end = E;
    if (b < B - 1) {
        int i1 = (b + 1) * NB1;
        end = scanned[i1] + bsum[i1 >> 10];
    }

    hist[t] = 0;
    __syncthreads();
    for (int i = start + t; i < end; i += 256)
        atomicAdd(&hist[(part[i] >> 17) & 255], 1);
    __syncthreads();

    int h = hist[t];
    ls[t] = h;
    __syncthreads();
    for (int o = 1; o < 256; o <<= 1) {
        int v = (t >= o) ? ls[t - o] : 0;
        __syncthreads();
        ls[t] += v;
        __syncthreads();
    }
    int excl = ls[t] - h;
    curs[t] = excl;
    int node = b * G_SIZE + t;
    if (node < N) offs[node] = start + excl;
    if (b == B - 1 && t == 0) offs[N] = E;
    __syncthreads();

    for (int i = start + t; i < end; i += 256) {
        int p = part[i];
        int pos = start + atomicAdd(&curs[(p >> 17) & 255], 1);
        if (pos >= 0 && pos < E) esrc[pos] = p & 0x1FFFF;
    }
}

// ---------------------------------------------------------------------------
// K4 (CSR): one wave per dst node, TWO-PHASE over 16-edge passes.
// R8 (passing): branch-free zero-padded 16-slot pass with ALL gathers issued
// before any consume (16 outstanding loads/wave) — unchanged this round.
// ---------------------------------------------------------------------------
__global__ __launch_bounds__(256) void k_aggr_csr(const int* __restrict__ offs,
                                                  const int* __restrict__ esrc,
                                                  const float* __restrict__ el,
                                                  const float* __restrict__ er,
                                                  const unsigned short* __restrict__ ftb,
                                                  const float* __restrict__ bias,
                                                  float* __restrict__ out,
                                                  int N) {
    int node = blockIdx.x * 4 + (threadIdx.x >> 6);
    if (node >= N) return;
    int lane = threadIdx.x & 63;
    int h1 = lane & 3;            // head this lane evaluates in phase 1
    int h2b = (lane >> 4) << 2;   // byte offset of this lane's output head
    float er1 = er[node * 4 + h1];

    int start = offs[node];
    int deg   = offs[node + 1] - start;

    float2 acc = make_float2(0.f, 0.f);
    float  wsum = 0.f;
    const unsigned int* ftu = (const unsigned int*)ftb;

    int p = 0;
    while (p < deg) {
        int cnt = min(16, deg - p);
        // ---- phase 1: lane group (4e..4e+3) computes (s, w) for edge p+e
        float w = 0.f;
        int   s = 0;
        int   e = lane >> 2;
        if (e < cnt) {
            s = esrc[start + p + e];
            float x = el[s * 4 + h1] + er1;
            x = x >= 0.f ? x : NEG_SLOPE * x;
            w = __expf(x);
        }
        // ---- phase 2: branch-free 16-slot pass, all gathers in flight
        float        wv[16];
        unsigned int uv[16];
#pragma unroll
        for (int j = 0; j < 16; ++j) {
            int ib = (j << 4) + h2b;   // byte idx of lane 4j + h2
            wv[j] = __int_as_float(
                __builtin_amdgcn_ds_bpermute(ib, __float_as_int(w)));
            int sj = __builtin_amdgcn_ds_bpermute(ib, s);
            uv[j] = ftu[(size_t)sj * 64 + lane];
        }
#pragma unroll
        for (int j = 0; j < 16; ++j) {
            wsum  += wv[j];
            acc.x += wv[j] * bf16_lo(uv[j]);
            acc.y += wv[j] * bf16_hi(uv[j]);
        }
        p += cnt;
    }
    float scale = 1.0f / fmaxf(wsum, 1e-16f);
    float2 bv = ((const float2*)bias)[lane];
    float2 o;
    o.x = acc.x * scale + bv.x;
    o.y = acc.y * scale + bv.y;
    ((float2*)out)[(size_t)node * 64 + lane] = o;
}

// ---------------------------------------------------------------------------
// Fallback (atomic) path — only if ws can't hold sort scratch.
// ---------------------------------------------------------------------------
__global__ __launch_bounds__(256) void k_init_fb(float* __restrict__ out,
                                                 const float* __restrict__ bias,
                                                 float* __restrict__ esum,
                                                 int n_out, int n_esum) {
    int i = blockIdx.x * 256 + threadIdx.x;
    if (i < n_out)  out[i]  = bias[i & 127];
    if (i < n_esum) esum[i] = 0.0f;
}

__global__ __launch_bounds__(256) void k_esum_fb(const int* __restrict__ src,
                                                 const int* __restrict__ dst,
                                                 const float* __restrict__ el,
                                                 const float* __restrict__ er,
                                                 float* __restrict__ esum,
                                                 int E4) {
    int i = blockIdx.x * 256 + threadIdx.x;
    if (i >= E4) return;
    int e = i >> 2, h = i & 3;
    int s = src[e], d = dst[e];
    float x = el[s * 4 + h] + er[d * 4 + h];
    x = x >= 0.f ? x : NEG_SLOPE * x;
    atomicAdd(&esum[d * 4 + h], __expf(x));
}

__global__ __launch_bounds__(256) void k_aggr_fb(const int* __restrict__ src,
                                                 const int* __restrict__ dst,
                                                 const float* __restrict__ el,
                                                 const float* __restrict__ er,
                                                 const float* __restrict__ esum,
                                                 const unsigned short* __restrict__ ftb,
                                                 float* __restrict__ out,
                                                 int E) {
    int i = blockIdx.x * 256 + threadIdx.x;
    int e = i >> 6;
    if (e >= E) return;
    int c = i & 63;
    int h = c >> 4;
    int s = src[e], d = dst[e];
    float x = el[s * 4 + h] + er[d * 4 + h];
    x = x >= 0.f ? x : NEG_SLOPE * x;
    float a = __expf(x) / fmaxf(esum[d * 4 + h], 1e-16f);
    unsigned int u = ((const unsigned int*)ftb)[(size_t)s * 64 + c];
    float* o = out + (size_t)d * 128 + c * 2;
    atomicAdd(o + 0, bf16_lo(u) * a);
    atomicAdd(o + 1, bf16_hi(u) * a);
}

// ---------------------------------------------------------------------------
extern "C" void kernel_launch(void* const* d_in, const int* in_sizes, int n_in,
                              void* d_out, int out_size, void* d_ws, size_t ws_size,
                              hipStream_t stream) {
    const float* feat   = (const float*)d_in[0];
    const int*   src    = (const int*)d_in[1];
    const int*   dst    = (const int*)d_in[2];
    const float* W      = (const float*)d_in[3];
    const float* attn_l = (const float*)d_in[4];
    const float* attn_r = (const float*)d_in[5];
    const float* bias   = (const float*)d_in[6];

    const int N  = in_sizes[0] / 256;   // 100000
    const int E  = in_sizes[1];         // 1600000
    const int NW = in_sizes[3];         // 32768
    float* out = (float*)d_out;

    const int B  = (N + G_SIZE - 1) / G_SIZE;       // 391 buckets
    const int CH = (E + NB1 - 1) / NB1;             // 6250 edges/chunk
    const int n2 = B * NB1;                         // 100096 count entries

    // ws layout: ftb[N*128 bf16] | Wb[NW bf16] | el[N*4] | er[N*4] |
    //            offs[N+1] | counts[n2] | scanned[n2] | bsum[256] |
    //            part[E] | esrc[E]
    unsigned short* ftb = (unsigned short*)d_ws;
    unsigned short* Wb  = ftb + (size_t)N * 128;
    float* el = (float*)(Wb + NW);
    float* er = el + (size_t)N * 4;
    int* offs    = (int*)(er + (size_t)N * 4);
    int* counts  = offs + (N + 1);
    int* scanned = counts + n2;
    int* bsum    = scanned + n2;
    int* part    = bsum + 256;
    int* esrc    = part + E;
    size_t need = (size_t)((char*)(esrc + E) - (char*)d_ws);

    k_wconv<<<(NW + 255) / 256, 256, 0, stream>>>(W, Wb, NW);
    k_gemm_mfma<<<(N + 63) / 64, 256, 0, stream>>>(feat, Wb, ftb, N);
    k_elr<<<(N * 4 + 255) / 256, 256, 0, stream>>>(ftb, attn_l, attn_r, el, er, N * 4);

    if (ws_size >= need) {
        const int NBs = (n2 + 1023) / 1024;   // 98 <= 256
        k_count<<<NB1, 256, 0, stream>>>(dst, counts, E, CH, B);
        k_scan1<<<NBs, 256, 0, stream>>>(counts, scanned, bsum, n2);   // out-of-place
        k_scan2<<<1, 256, 0, stream>>>(bsum, NBs);
        k_partition<<<NB1, 256, 0, stream>>>(src, dst, scanned, bsum, part, E, CH, B);
        k_bucket<<<B, 256, 0, stream>>>(scanned, bsum, part, offs, esrc, E, B, N);
        k_aggr_csr<<<(N + 3) / 4, 256, 0, stream>>>(offs, esrc, el, er, ftb, bias, out, N);
    } else {
        float* esum = (float*)(er + (size_t)N * 4);
        k_init_fb<<<(N * 128 + 255) / 256, 256, 0, stream>>>(out, bias, esum, N * 128, N * 4);
        k_esum_fb<<<(E * 4 + 255) / 256, 256, 0, stream>>>(src, dst, el, er, esum, E * 4);
        k_aggr_fb<<<((size_t)E * 64 + 255) / 256, 256, 0, stream>>>(src, dst, el, er, esum, ftb, out, E);
    }
}